// Round 10
// baseline (144.313 us; speedup 1.0000x reference)
//
#include <hip/hip_runtime.h>

#define NCLASS 1000
#define D 64
#define WARMUP 1000
#define NB 256              // partition blocks (1 per CU)
#define LAB_MAX 7936        // per-block label cache (needs n <= NB*LAB_MAX)
#define K4_TPB 256          // 4 waves; 4+ blocks/CU -> all 1000 classes resident
#define UNR 4               // k4: outstanding row-loads per thread

typedef float f32x4 __attribute__((ext_vector_type(4)));
typedef float f32x8 __attribute__((ext_vector_type(8)));

// ws layout (bytes)
#define OFF_CNT   0          // NCLASS*NB ints (1.024 MB)  [c][b]
#define OFF_LOFF  1048576    // NCLASS*NB ints (1.024 MB)  [c][b]
#define OFF_TOT   2097152    // NCLASS ints
#define OFF_BASE  2101248    // NCLASS ints
#define OFF_SORT  2105344    // n ints (8 MB)

// ---------------------------------------------------------------------------
// K1: per-block label histogram -> cnt_t[c * NB + b]  (transposed layout)
__global__ __launch_bounds__(512)
void k1_hist(const int* __restrict__ label, int n, int rpb,
             int* __restrict__ cnt_t)
{
    __shared__ int hist[NCLASS];
    const int b = blockIdx.x, tid = threadIdx.x;
    for (int i = tid; i < NCLASS; i += 512) hist[i] = 0;
    __syncthreads();
    const int r0 = b * rpb, r1 = min(n, r0 + rpb);
    for (int r = r0 + tid; r < r1; r += 512)
        atomicAdd(&hist[label[r]], 1);
    __syncthreads();
    for (int i = tid; i < NCLASS; i += 512)
        cnt_t[i * NB + b] = hist[i];
}

// ---------------------------------------------------------------------------
// K2: per-class exclusive scan across blocks -> loff_t[c][b]; last inclusive
// element is the class total.
__global__ __launch_bounds__(NB)
void k2_offsets(const int* __restrict__ cnt_t,
                int* __restrict__ loff_t, int* __restrict__ totals)
{
    __shared__ int buf[NB];
    const int c = blockIdx.x, t = threadIdx.x;
    const int v0 = cnt_t[c * NB + t];
    buf[t] = v0;
    __syncthreads();
    for (int off = 1; off < NB; off <<= 1) {
        const int v = (t >= off) ? buf[t - off] : 0;
        __syncthreads();
        buf[t] += v;
        __syncthreads();
    }
    loff_t[c * NB + t] = buf[t] - v0;
    if (t == NB - 1) totals[c] = buf[t];
}

// ---------------------------------------------------------------------------
// K3: write-coalesced scatter (LDS counting-sort then ordered write-out).
__global__ __launch_bounds__(1024)
void k3_scatter(const int* __restrict__ label, int n, int rpb,
                const int* __restrict__ loff_t, const int* __restrict__ totals,
                int* __restrict__ sorted_idx, int* __restrict__ base_out)
{
    __shared__ int lab[LAB_MAX];     // chunk labels
    __shared__ int loc[LAB_MAX];     // locally sorted local row ids
    __shared__ int lstart[NCLASS];   // local class start (excl scan of hist)
    __shared__ int cursor[NCLASS];   // hist -> scatter cursor -> combo
    __shared__ int sbuf[1024];       // scan scratch

    const int b = blockIdx.x, tid = threadIdx.x;
    const int r0 = b * rpb;
    const int cn = min(n - r0, rpb);

    // P1: cache labels, local histogram (in `cursor`)
    for (int i = tid; i < cn; i += 1024) lab[i] = label[r0 + i];
    if (tid < NCLASS) cursor[tid] = 0;
    __syncthreads();
    for (int i = tid; i < cn; i += 1024) atomicAdd(&cursor[lab[i]], 1);
    __syncthreads();

    // P2: exclusive scan of local hist -> lstart; reset cursor to lstart
    {
        const int mine = (tid < NCLASS) ? cursor[tid] : 0;
        sbuf[tid] = mine;
        __syncthreads();
        for (int off = 1; off < 1024; off <<= 1) {
            const int add = (tid >= off) ? sbuf[tid - off] : 0;
            __syncthreads();
            sbuf[tid] += add;
            __syncthreads();
        }
        if (tid < NCLASS) {
            lstart[tid] = sbuf[tid] - mine;
            cursor[tid] = sbuf[tid] - mine;
        }
    }
    __syncthreads();

    // P3: local scatter into loc[] (LDS only)
    for (int i = tid; i < cn; i += 1024) {
        const int p = atomicAdd(&cursor[lab[i]], 1);
        loc[p] = i;
    }
    __syncthreads();

    // P4: global base scan (over totals) + combo = base + loff - lstart
    {
        const int mine = (tid < NCLASS) ? totals[tid] : 0;
        sbuf[tid] = mine;
        __syncthreads();
        for (int off = 1; off < 1024; off <<= 1) {
            const int add = (tid >= off) ? sbuf[tid - off] : 0;
            __syncthreads();
            sbuf[tid] += add;
            __syncthreads();
        }
        if (tid < NCLASS) {
            const int bs = sbuf[tid] - mine;
            if (b == 0) base_out[tid] = bs;
            cursor[tid] = bs + loff_t[tid * NB + b] - lstart[tid];
        }
    }
    __syncthreads();

    // P5: ordered write-out — consecutive k -> consecutive addr within runs
    for (int k = tid; k < cn; k += 1024) {
        const int lr = loc[k];
        const int c  = lab[lr];
        sorted_idx[cursor[c] + k] = r0 + lr;
    }
}

// ---------------------------------------------------------------------------
// K4: one 256-thread block per class, all 1000 blocks co-resident (4/CU) so
// every class sweeps the feature array in lockstep. f32x8 (32B) loads:
// 8 lanes per row -> 8 rows per wave load, half the VMEM instructions and
// 128B in flight per thread. Register accumulate, shuffle+LDS reduce,
// fused mean/EMA finalize.
// Thread layout: slot = tid>>3 (32 row slots), col = tid&7 (f32x8 column).
__global__ __launch_bounds__(K4_TPB, 4)
void k4_reduce(const float* __restrict__ feat, const int* __restrict__ sorted_idx,
               const int* __restrict__ base, const int* __restrict__ totals,
               const float* __restrict__ proto, const int* __restrict__ step_ptr,
               float* __restrict__ out)
{
    __shared__ float red[4][D];
    const int c   = blockIdx.x;
    const int cnt = totals[c];
    const int st  = base[c];
    const int tid = threadIdx.x;
    const int slot = tid >> 3;               // 0..31
    const int col  = tid & 7;

    f32x8 acc0 = {0.f,0.f,0.f,0.f,0.f,0.f,0.f,0.f};
    f32x8 acc1 = {0.f,0.f,0.f,0.f,0.f,0.f,0.f,0.f};
    int j = slot;
    for (; j + (UNR - 1) * 32 < cnt; j += UNR * 32) {
        int rr[UNR];
        #pragma unroll
        for (int u = 0; u < UNR; ++u)
            rr[u] = __builtin_nontemporal_load(sorted_idx + st + j + u * 32);
        f32x8 v[UNR];
        #pragma unroll
        for (int u = 0; u < UNR; ++u)
            v[u] = __builtin_nontemporal_load((const f32x8*)(feat + (size_t)rr[u] * D + col * 8));
        #pragma unroll
        for (int u = 0; u < UNR; u += 2) {
            acc0 += v[u];
            acc1 += v[u + 1];
        }
    }
    for (; j < cnt; j += 32) {
        const int r = sorted_idx[st + j];
        acc0 += __builtin_nontemporal_load((const f32x8*)(feat + (size_t)r * D + col * 8));
    }
    acc0 += acc1;

    // reduce the 8 slots within each wave (slot spans tid bits 3-5)
    #pragma unroll
    for (int m = 8; m <= 32; m <<= 1) {
        #pragma unroll
        for (int q = 0; q < 8; ++q)
            acc0[q] += __shfl_xor(acc0[q], m);
    }
    const int wv = tid >> 6;                 // wave id 0..3
    if ((tid & 63) < 8) {                    // lanes 0..7 hold col sums
        #pragma unroll
        for (int q = 0; q < 8; ++q)
            red[wv][col * 8 + q] = acc0[q];
    }
    __syncthreads();

    if (tid < D) {
        float s = 0.f;
        #pragma unroll
        for (int k = 0; k < 4; ++k) s += red[k][tid];
        const float mean = s / (float)(cnt > 0 ? cnt : 1);
        const float p    = proto[c * D + tid];
        const unsigned long long nz = __ballot(p != 0.0f);
        const bool use_new = (nz == 0ULL) || (step_ptr[0] <= WARMUP);
        const float upd = use_new ? mean : (0.9f * p + 0.1f * mean);
        out[c * D + tid] = (cnt > 0) ? upd : p;
    }
}

// ---------------------------------------------------------------------------
extern "C" void kernel_launch(void* const* d_in, const int* in_sizes, int n_in,
                              void* d_out, int out_size, void* d_ws, size_t ws_size,
                              hipStream_t stream)
{
    const float* proto = (const float*)d_in[0];
    const float* feat  = (const float*)d_in[1];
    const int*   label = (const int*)d_in[2];
    const int*   step  = (const int*)d_in[3];
    float* out = (float*)d_out;
    const int n = in_sizes[2];

    char* ws = (char*)d_ws;
    int* cnt_t  = (int*)(ws + OFF_CNT);
    int* loff_t = (int*)(ws + OFF_LOFF);
    int* totals = (int*)(ws + OFF_TOT);
    int* base   = (int*)(ws + OFF_BASE);
    int* sorted = (int*)(ws + OFF_SORT);
    (void)ws_size;

    const int rpb = (n + NB - 1) / NB;       // 7813 for n=2M; fits LAB_MAX

    k1_hist   <<<NB, 512, 0, stream>>>(label, n, rpb, cnt_t);
    k2_offsets<<<NCLASS, NB, 0, stream>>>(cnt_t, loff_t, totals);
    k3_scatter<<<NB, 1024, 0, stream>>>(label, n, rpb, loff_t, totals,
                                        sorted, base);
    k4_reduce <<<NCLASS, K4_TPB, 0, stream>>>(feat, sorted, base, totals,
                                              proto, step, out);
}

// Round 11
// 115.889 us; speedup vs baseline: 1.2453x; 1.2453x over previous
//
#include <hip/hip_runtime.h>

#define NCLASS 1000
#define D 64
#define WARMUP 1000
#define NB 256              // partition blocks (1 per CU)
#define LAB_MAX 7936        // per-block label cache (needs n <= NB*LAB_MAX)
#define K4_TPB 256          // 4 waves; 8 blocks/CU -> all 1000 classes resident
#define UNR 4               // k4: outstanding row-loads per thread

typedef float f32x4 __attribute__((ext_vector_type(4)));

// ws layout (bytes)
#define OFF_CNT   0          // NCLASS*NB ints (1.024 MB)  [c][b]
#define OFF_LOFF  1048576    // NCLASS*NB ints (1.024 MB)  [c][b]
#define OFF_TOT   2097152    // NCLASS ints
#define OFF_BASE  2101248    // NCLASS ints
#define OFF_SORT  2105344    // n ints (8 MB)

// ---------------------------------------------------------------------------
// K1: per-block label histogram -> cnt_t[c * NB + b]  (transposed layout)
__global__ __launch_bounds__(512)
void k1_hist(const int* __restrict__ label, int n, int rpb,
             int* __restrict__ cnt_t)
{
    __shared__ int hist[NCLASS];
    const int b = blockIdx.x, tid = threadIdx.x;
    for (int i = tid; i < NCLASS; i += 512) hist[i] = 0;
    __syncthreads();
    const int r0 = b * rpb, r1 = min(n, r0 + rpb);
    for (int r = r0 + tid; r < r1; r += 512)
        atomicAdd(&hist[label[r]], 1);
    __syncthreads();
    for (int i = tid; i < NCLASS; i += 512)
        cnt_t[i * NB + b] = hist[i];
}

// ---------------------------------------------------------------------------
// K2: per-class exclusive scan across blocks -> loff_t[c][b]; last inclusive
// element is the class total.
__global__ __launch_bounds__(NB)
void k2_offsets(const int* __restrict__ cnt_t,
                int* __restrict__ loff_t, int* __restrict__ totals)
{
    __shared__ int buf[NB];
    const int c = blockIdx.x, t = threadIdx.x;
    const int v0 = cnt_t[c * NB + t];
    buf[t] = v0;
    __syncthreads();
    for (int off = 1; off < NB; off <<= 1) {
        const int v = (t >= off) ? buf[t - off] : 0;
        __syncthreads();
        buf[t] += v;
        __syncthreads();
    }
    loff_t[c * NB + t] = buf[t] - v0;
    if (t == NB - 1) totals[c] = buf[t];
}

// ---------------------------------------------------------------------------
// K3: write-coalesced scatter (LDS counting-sort then ordered write-out).
__global__ __launch_bounds__(1024)
void k3_scatter(const int* __restrict__ label, int n, int rpb,
                const int* __restrict__ loff_t, const int* __restrict__ totals,
                int* __restrict__ sorted_idx, int* __restrict__ base_out)
{
    __shared__ int lab[LAB_MAX];     // chunk labels
    __shared__ int loc[LAB_MAX];     // locally sorted local row ids
    __shared__ int lstart[NCLASS];   // local class start (excl scan of hist)
    __shared__ int cursor[NCLASS];   // hist -> scatter cursor -> combo
    __shared__ int sbuf[1024];       // scan scratch

    const int b = blockIdx.x, tid = threadIdx.x;
    const int r0 = b * rpb;
    const int cn = min(n - r0, rpb);

    // P1: cache labels, local histogram (in `cursor`)
    for (int i = tid; i < cn; i += 1024) lab[i] = label[r0 + i];
    if (tid < NCLASS) cursor[tid] = 0;
    __syncthreads();
    for (int i = tid; i < cn; i += 1024) atomicAdd(&cursor[lab[i]], 1);
    __syncthreads();

    // P2: exclusive scan of local hist -> lstart; reset cursor to lstart
    {
        const int mine = (tid < NCLASS) ? cursor[tid] : 0;
        sbuf[tid] = mine;
        __syncthreads();
        for (int off = 1; off < 1024; off <<= 1) {
            const int add = (tid >= off) ? sbuf[tid - off] : 0;
            __syncthreads();
            sbuf[tid] += add;
            __syncthreads();
        }
        if (tid < NCLASS) {
            lstart[tid] = sbuf[tid] - mine;
            cursor[tid] = sbuf[tid] - mine;
        }
    }
    __syncthreads();

    // P3: local scatter into loc[] (LDS only)
    for (int i = tid; i < cn; i += 1024) {
        const int p = atomicAdd(&cursor[lab[i]], 1);
        loc[p] = i;
    }
    __syncthreads();

    // P4: global base scan (over totals) + combo = base + loff - lstart
    {
        const int mine = (tid < NCLASS) ? totals[tid] : 0;
        sbuf[tid] = mine;
        __syncthreads();
        for (int off = 1; off < 1024; off <<= 1) {
            const int add = (tid >= off) ? sbuf[tid - off] : 0;
            __syncthreads();
            sbuf[tid] += add;
            __syncthreads();
        }
        if (tid < NCLASS) {
            const int bs = sbuf[tid] - mine;
            if (b == 0) base_out[tid] = bs;
            cursor[tid] = bs + loff_t[tid * NB + b] - lstart[tid];
        }
    }
    __syncthreads();

    // P5: ordered write-out — consecutive k -> consecutive addr within runs
    for (int k = tid; k < cn; k += 1024) {
        const int lr = loc[k];
        const int c  = lab[lr];
        sorted_idx[cursor[c] + k] = r0 + lr;
    }
}

// ---------------------------------------------------------------------------
// K4 (R9 configuration — best measured): one 256-thread block per class,
// all 1000 blocks co-resident (8/CU) so every class sweeps the feature
// array in lockstep — aggregate DRAM access is a tight moving window.
// 16 lanes x 16B per row: one fully-contiguous 256B row per 16-lane group
// per instruction (R10's f32x8 variant split this into stride-32B halves
// and regressed 25%). Register accumulate, shuffle+LDS reduce, fused EMA.
// Thread layout: slot = tid>>4 (16 row slots), col = tid&15 (float4 column).
__global__ __launch_bounds__(K4_TPB, 8)
void k4_reduce(const float* __restrict__ feat, const int* __restrict__ sorted_idx,
               const int* __restrict__ base, const int* __restrict__ totals,
               const float* __restrict__ proto, const int* __restrict__ step_ptr,
               float* __restrict__ out)
{
    __shared__ float red[4][D];
    const int c   = blockIdx.x;
    const int cnt = totals[c];
    const int st  = base[c];
    const int tid = threadIdx.x;
    const int slot = tid >> 4;               // 0..15
    const int col  = tid & 15;

    f32x4 acc0 = {0.f, 0.f, 0.f, 0.f};
    f32x4 acc1 = {0.f, 0.f, 0.f, 0.f};
    int j = slot;
    for (; j + (UNR - 1) * 16 < cnt; j += UNR * 16) {
        int rr[UNR];
        #pragma unroll
        for (int u = 0; u < UNR; ++u)
            rr[u] = sorted_idx[st + j + u * 16];
        f32x4 v[UNR];
        #pragma unroll
        for (int u = 0; u < UNR; ++u)
            v[u] = __builtin_nontemporal_load((const f32x4*)(feat + (size_t)rr[u] * D + col * 4));
        #pragma unroll
        for (int u = 0; u < UNR; u += 2) {
            acc0 += v[u];
            acc1 += v[u + 1];
        }
    }
    for (; j < cnt; j += 16) {
        const int r = sorted_idx[st + j];
        acc0 += __builtin_nontemporal_load((const f32x4*)(feat + (size_t)r * D + col * 4));
    }
    acc0 += acc1;

    // reduce the 4 slots within each wave (slot differs in tid bits 4-5)
    #pragma unroll
    for (int m = 16; m <= 32; m <<= 1) {
        acc0[0] += __shfl_xor(acc0[0], m);
        acc0[1] += __shfl_xor(acc0[1], m);
        acc0[2] += __shfl_xor(acc0[2], m);
        acc0[3] += __shfl_xor(acc0[3], m);
    }
    const int wv = tid >> 6;                 // wave id 0..3
    if ((tid & 63) < 16) {                   // lanes 0..15 hold col sums
        red[wv][col * 4 + 0] = acc0[0];
        red[wv][col * 4 + 1] = acc0[1];
        red[wv][col * 4 + 2] = acc0[2];
        red[wv][col * 4 + 3] = acc0[3];
    }
    __syncthreads();

    if (tid < D) {
        float s = 0.f;
        #pragma unroll
        for (int k = 0; k < 4; ++k) s += red[k][tid];
        const float mean = s / (float)(cnt > 0 ? cnt : 1);
        const float p    = proto[c * D + tid];
        const unsigned long long nz = __ballot(p != 0.0f);
        const bool use_new = (nz == 0ULL) || (step_ptr[0] <= WARMUP);
        const float upd = use_new ? mean : (0.9f * p + 0.1f * mean);
        out[c * D + tid] = (cnt > 0) ? upd : p;
    }
}

// ---------------------------------------------------------------------------
extern "C" void kernel_launch(void* const* d_in, const int* in_sizes, int n_in,
                              void* d_out, int out_size, void* d_ws, size_t ws_size,
                              hipStream_t stream)
{
    const float* proto = (const float*)d_in[0];
    const float* feat  = (const float*)d_in[1];
    const int*   label = (const int*)d_in[2];
    const int*   step  = (const int*)d_in[3];
    float* out = (float*)d_out;
    const int n = in_sizes[2];

    char* ws = (char*)d_ws;
    int* cnt_t  = (int*)(ws + OFF_CNT);
    int* loff_t = (int*)(ws + OFF_LOFF);
    int* totals = (int*)(ws + OFF_TOT);
    int* base   = (int*)(ws + OFF_BASE);
    int* sorted = (int*)(ws + OFF_SORT);
    (void)ws_size;

    const int rpb = (n + NB - 1) / NB;       // 7813 for n=2M; fits LAB_MAX

    k1_hist   <<<NB, 512, 0, stream>>>(label, n, rpb, cnt_t);
    k2_offsets<<<NCLASS, NB, 0, stream>>>(cnt_t, loff_t, totals);
    k3_scatter<<<NB, 1024, 0, stream>>>(label, n, rpb, loff_t, totals,
                                        sorted, base);
    k4_reduce <<<NCLASS, K4_TPB, 0, stream>>>(feat, sorted, base, totals,
                                              proto, step, out);
}